// Round 7
// baseline (107.467 us; speedup 1.0000x reference)
//
#include <hip/hip_runtime.h>
#include <hip/hip_bf16.h>

typedef float f32x4 __attribute__((ext_vector_type(4)));
typedef float f32x16 __attribute__((ext_vector_type(16)));
typedef __bf16 bf16x8 __attribute__((ext_vector_type(8)));
typedef __bf16 bf16x4 __attribute__((ext_vector_type(4)));
typedef unsigned int uint2v __attribute__((ext_vector_type(2)));

constexpr int B_ = 8, C_ = 256, N_ = 2048, H_ = 4, D_ = 64;
constexpr int BH_ = B_ * H_;  // 32
constexpr size_t PER_ = (size_t)BH_ * N_ * D_;  // 4M elems
constexpr float LOG2E = 1.44269504088896340736f;

static __device__ __forceinline__ float fast_exp2(float x) {
#if __has_builtin(__builtin_amdgcn_exp2f)
  return __builtin_amdgcn_exp2f(x);
#else
  return exp2f(x);
#endif
}

// XOR swizzle for [rows][128B] LDS tiles: spread 16B slots across banks.
// Applied on BOTH write and read (reg-staged, rule #21).
static __device__ __forceinline__ void* swz(void* base, int row, int cb) {
  return (char*)base + row * 128 + (cb ^ ((row & 7) << 4));
}
static __device__ __forceinline__ const void* swz(const void* base, int row, int cb) {
  return (const char*)base + row * 128 + (cb ^ ((row & 7) << 4));
}

// ---------------------------------------------------------------------------
// W pre-convert -> bf16 A-fragment order (16x16 frags for the GEMM kernels).
// ---------------------------------------------------------------------------
struct W4 {
  const float* s0; const float* s1; const float* s2; const float* s3;
  __bf16* d0; __bf16* d1; __bf16* d2; __bf16* d3;
};

__global__ __launch_bounds__(256) void wcvt_kernel(W4 p) {
  const int m = blockIdx.y;
  const float* src = m == 0 ? p.s0 : m == 1 ? p.s1 : m == 2 ? p.s2 : p.s3;
  __bf16* dst = m == 0 ? p.d0 : m == 1 ? p.d1 : m == 2 ? p.d2 : p.d3;
  const int f = blockIdx.x * 256 + threadIdx.x;  // 0..8191 fragment ids
  const int o_blk = f >> 9;
  const int ks = (f >> 6) & 7;
  const int lane = f & 63;
  const int row = o_blk * 16 + (lane & 15);
  const int kbase = ks * 32 + (lane >> 4) * 8;
  bf16x8 v;
  if (m == 3) {
    for (int e = 0; e < 8; e++) {
      const int k = kbase + e;
      const int c = ((k & 63) << 2) | (k >> 6);
      v[e] = (__bf16)src[row * 256 + c];
    }
  } else {
    const int srow = ((row & 63) << 2) | (row >> 6);  // orig channel d*4+h
    const float* s = src + srow * 256 + kbase;
    float4 a = *(const float4*)s;
    float4 b = *(const float4*)(s + 4);
    v[0] = (__bf16)a.x; v[1] = (__bf16)a.y; v[2] = (__bf16)a.z; v[3] = (__bf16)a.w;
    v[4] = (__bf16)b.x; v[5] = (__bf16)b.y; v[6] = (__bf16)b.z; v[7] = (__bf16)b.w;
  }
  *(bf16x8*)&dst[(size_t)f * 8] = v;
}

// ---------------------------------------------------------------------------
// Fused QKV projection (unchanged).
// ---------------------------------------------------------------------------
__global__ __launch_bounds__(256) void qkv_fused_kernel(
    const float* __restrict__ xq, const float* __restrict__ xk,
    const float* __restrict__ xv, const __bf16* __restrict__ wfq,
    const __bf16* __restrict__ wfk, const __bf16* __restrict__ wfv,
    const float* __restrict__ bq, const float* __restrict__ bk,
    const float* __restrict__ bv, __bf16* __restrict__ oq,
    __bf16* __restrict__ ok, __bf16* __restrict__ ov) {
  __shared__ __bf16 xlds[64][264];

  const int m = blockIdx.x >> 8;
  int inner = blockIdx.x & 255;
  inner = (inner & 7) * 32 + (inner >> 3);  // bijective XCD swizzle (256=8*32)
  const int b = inner >> 5, nb = inner & 31;
  const int n0 = nb * 64;

  const float* xf = m == 0 ? xq : m == 1 ? xk : xv;
  const __bf16* wf = m == 0 ? wfq : m == 1 ? wfk : wfv;
  const float* bias = m == 0 ? bq : m == 1 ? bk : bv;
  __bf16* out = m == 0 ? oq : m == 1 ? ok : ov;
  const float scale = m == 0 ? 0.125f * LOG2E : 1.0f;

  const int t = threadIdx.x;
  {
    const int kl = t >> 4;         // 0..15
    const int nl = (t & 15) * 4;   // 0,4,..,60
    const float* src = xf + (size_t)b * C_ * N_ + n0 + nl;
    for (int it = 0; it < 16; it++) {
      const int k = it * 16 + kl;
      float4 f = *(const float4*)(src + (size_t)k * N_);
      xlds[nl + 0][k] = (__bf16)f.x;
      xlds[nl + 1][k] = (__bf16)f.y;
      xlds[nl + 2][k] = (__bf16)f.z;
      xlds[nl + 3][k] = (__bf16)f.w;
    }
  }
  __syncthreads();

  const int lane = t & 63, wvv = t >> 6;
  const int wm = wvv >> 1, wn = wvv & 1;   // wave: 128 o x 32 n
  const int l15 = lane & 15, lg = lane >> 4;

  f32x4 acc[8][2] = {};

  for (int ks = 0; ks < 8; ks++) {
    bf16x8 bfr[2];
    for (int ni = 0; ni < 2; ni++)
      bfr[ni] = *(const bf16x8*)&xlds[wn * 32 + ni * 16 + l15][ks * 32 + lg * 8];
    for (int mi = 0; mi < 8; mi++) {
      bf16x8 af = *(const bf16x8*)&wf[(((size_t)(wm * 8 + mi) * 8 + ks) * 64 + lane) * 8];
      acc[mi][0] = __builtin_amdgcn_mfma_f32_16x16x32_bf16(af, bfr[0], acc[mi][0], 0, 0, 0);
      acc[mi][1] = __builtin_amdgcn_mfma_f32_16x16x32_bf16(af, bfr[1], acc[mi][1], 0, 0, 0);
    }
  }

  for (int mi = 0; mi < 8; mi++) {
    const int h = wm * 2 + (mi >> 2);
    const int d0 = (mi & 3) * 16 + 4 * lg;
    for (int ni = 0; ni < 2; ni++) {
      const int n = n0 + wn * 32 + ni * 16 + l15;
      if (m != 2) {
        bf16x4 o4;
        for (int r = 0; r < 4; r++)
          o4[r] = (__bf16)((acc[mi][ni][r] + bias[((d0 + r) << 2) | h]) * scale);
        *(bf16x4*)&out[((size_t)(b * H_ + h) * N_ + n) * D_ + d0] = o4;
      } else {
        for (int r = 0; r < 4; r++)
          out[((size_t)(b * H_ + h) * D_ + d0 + r) * N_ + n] =
              (__bf16)(acc[mi][ni][r] + bias[((d0 + r) << 2) | h]);
      }
    }
  }
}

// ---------------------------------------------------------------------------
// Final projection: y[o,n] = sum_k w'[o,k]*attout[.] + bm[o], f32 out.
// attout layout: [b*H+h][n][64] with k = h*64+d.
// ---------------------------------------------------------------------------
__global__ __launch_bounds__(256) void final_proj_kernel(
    const __bf16* __restrict__ xb, const __bf16* __restrict__ wf,
    const float* __restrict__ bias, float* __restrict__ out) {
  const int bid = blockIdx.x;
  const int wid = (bid & 7) * 128 + (bid >> 3);
  const int o_t = wid & 3;
  const int nb = (wid >> 2) & 31;
  const int b = wid >> 7;
  const int o0 = o_t * 64, n0 = nb * 64;
  const int t = threadIdx.x, lane = t & 63;
  const int wvv = t >> 6, wm = wvv >> 1, wn = wvv & 1;
  const int l15 = lane & 15, lg = lane >> 4;
  const int nbase = n0 + wn * 32 + l15;

  f32x4 acc[2][2] = {};

  for (int ks = 0; ks < 8; ks++) {
    bf16x8 af[2];
    for (int mi = 0; mi < 2; mi++)
      af[mi] = *(const bf16x8*)&wf[(((size_t)(o_t * 4 + wm * 2 + mi) * 8 + ks) * 64 + lane) * 8];
    bf16x8 bfr[2];
    const size_t bh = (size_t)(b * H_ + (ks >> 1));
    const int d0 = (ks & 1) * 32 + lg * 8;
    for (int ni = 0; ni < 2; ni++)
      bfr[ni] = *(const bf16x8*)&xb[(bh * N_ + nbase + ni * 16) * D_ + d0];
    for (int mi = 0; mi < 2; mi++)
      for (int ni = 0; ni < 2; ni++)
        acc[mi][ni] = __builtin_amdgcn_mfma_f32_16x16x32_bf16(
            af[mi], bfr[ni], acc[mi][ni], 0, 0, 0);
  }

  for (int mi = 0; mi < 2; mi++) {
    for (int r = 0; r < 4; r++) {
      const int och = o0 + wm * 32 + mi * 16 + 4 * lg + r;
      const float bv_ = bias[och];
      for (int ni = 0; ni < 2; ni++) {
        const int n = n0 + wn * 32 + ni * 16 + l15;
        out[((size_t)b * C_ + och) * N_ + n] = acc[mi][ni][r] + bv_;
      }
    }
  }
}

// ---------------------------------------------------------------------------
// Flash attention, 32x32 MFMA, in-register P (permlane32_swap), maxless
// softmax. SPLIT-way KV split: each block handles N_/SPLIT kv rows, writes
// UNNORMALIZED partial O (bf16) + partial l; combine kernel normalizes.
// SPLIT==1: normalizes in-kernel (fallback when workspace is small).
// ---------------------------------------------------------------------------
template <int SPLIT>
__global__ __launch_bounds__(256) void attn_kernel(
    const __bf16* __restrict__ qb, const __bf16* __restrict__ kb,
    const __bf16* __restrict__ vtb, __bf16* __restrict__ pO,
    float* __restrict__ lbuf) {
  __shared__ __bf16 kbuf[2][64][64];
  __shared__ __bf16 vtbuf[2][64][64];

  const int t = threadIdx.x, lane = t & 63, wv = t >> 6;
  const int l31 = lane & 31, hi = lane >> 5;

  const int bid = blockIdx.x;                  // 512*SPLIT blocks
  const int s = (SPLIT > 1) ? (bid >> 9) : 0;
  const int inner = bid & 511;
  const int wid = (inner & 7) * 64 + (inner >> 3);  // XCD swizzle
  const int bh = wid >> 4;
  const int qn = (wid & 15) * 128 + wv * 32;   // wave's 32 q rows
  const int jbase = s * (N_ / SPLIT);
  constexpr int NT = N_ / SPLIT / 64;          // tiles per block

  const __bf16* k_bh = kb + (size_t)bh * N_ * D_;
  const __bf16* vt_bh = vtb + (size_t)bh * D_ * N_;

  // Q B-frags: qf[i] = Q[q=qn+l31][d = i*16 + hi*8 .. +7]
  const __bf16* qrow = qb + ((size_t)bh * N_ + qn + l31) * D_;
  bf16x8 qf[4];
#pragma unroll
  for (int i = 0; i < 4; i++) qf[i] = *(const bf16x8*)(qrow + i * 16 + hi * 8);

  const int srow = t >> 2, sce = (t & 3) * 16;  // staging: row, elem-col

  // prologue: stage tile 0 -> buf0
  {
    uint4 ka = *(const uint4*)(k_bh + (size_t)(jbase + srow) * D_ + sce);
    uint4 kc = *(const uint4*)(k_bh + (size_t)(jbase + srow) * D_ + sce + 8);
    uint4 va = *(const uint4*)(vt_bh + (size_t)srow * N_ + jbase + sce);
    uint4 vc = *(const uint4*)(vt_bh + (size_t)srow * N_ + jbase + sce + 8);
    *(uint4*)swz(&kbuf[0][0][0], srow, sce * 2) = ka;
    *(uint4*)swz(&kbuf[0][0][0], srow, sce * 2 + 16) = kc;
    *(uint4*)swz(&vtbuf[0][0][0], srow, sce * 2) = va;
    *(uint4*)swz(&vtbuf[0][0][0], srow, sce * 2 + 16) = vc;
  }
  __syncthreads();

  f32x16 o0 = {}, o1 = {};
  float la0 = 0.f, la1 = 0.f, la2 = 0.f, la3 = 0.f;
  int cur = 0;

  for (int jt = 0; jt < NT; jt++) {
    const int j0 = jbase + jt * 64;
    const bool have = (jt + 1) < NT;
    uint4 pka, pkc, pva, pvc;
    if (have) {  // T14: issue next-tile loads early; write after compute
      const int jn = j0 + 64;
      pka = *(const uint4*)(k_bh + (size_t)(jn + srow) * D_ + sce);
      pkc = *(const uint4*)(k_bh + (size_t)(jn + srow) * D_ + sce + 8);
      pva = *(const uint4*)(vt_bh + (size_t)srow * N_ + jn + sce);
      pvc = *(const uint4*)(vt_bh + (size_t)srow * N_ + jn + sce + 8);
    }

    // QK: two 32x32 S-subtiles (k rows j0.. and j0+32..)
    f32x16 s0 = {}, s1 = {};
    __builtin_amdgcn_s_setprio(1);
#pragma unroll
    for (int i = 0; i < 4; i++) {
      bf16x8 kf = *(const bf16x8*)swz(&kbuf[cur][0][0], l31, i * 32 + hi * 16);
      s0 = __builtin_amdgcn_mfma_f32_32x32x16_bf16(kf, qf[i], s0, 0, 0, 0);
    }
#pragma unroll
    for (int i = 0; i < 4; i++) {
      bf16x8 kf = *(const bf16x8*)swz(&kbuf[cur][0][0], 32 + l31, i * 32 + hi * 16);
      s1 = __builtin_amdgcn_mfma_f32_32x32x16_bf16(kf, qf[i], s1, 0, 0, 0);
    }
    __builtin_amdgcn_s_setprio(0);

    // per-subtile: exp2 -> pack bf16 pairs -> permlane32_swap -> PV
#pragma unroll
    for (int sub = 0; sub < 2; sub++) {
      const f32x16 sv = sub ? s1 : s0;
      float pr[16];
#pragma unroll
      for (int r = 0; r < 16; r++) pr[r] = fast_exp2(sv[r]);
      la0 += pr[0] + pr[4] + pr[8] + pr[12];
      la1 += pr[1] + pr[5] + pr[9] + pr[13];
      la2 += pr[2] + pr[6] + pr[10] + pr[14];
      la3 += pr[3] + pr[7] + pr[11] + pr[15];
      unsigned w[8];
#pragma unroll
      for (int g = 0; g < 8; g++) {
        union { __bf16 h[2]; unsigned u; } cv;
        cv.h[0] = (__bf16)pr[2 * g];
        cv.h[1] = (__bf16)pr[2 * g + 1];
        w[g] = cv.u;
      }
      // B-frag redistribution: lane needs P[k=hi*8+e][q=l31]
      uint2v r0 = __builtin_amdgcn_permlane32_swap(w[0], w[2], false, false);
      uint2v r1 = __builtin_amdgcn_permlane32_swap(w[1], w[3], false, false);
      uint2v r2 = __builtin_amdgcn_permlane32_swap(w[4], w[6], false, false);
      uint2v r3 = __builtin_amdgcn_permlane32_swap(w[5], w[7], false, false);
      union { unsigned u[4]; bf16x8 v; } f0 = {{r0.x, r1.x, r0.y, r1.y}};  // k 0..15
      union { unsigned u[4]; bf16x8 v; } f1 = {{r2.x, r3.x, r2.y, r3.y}};  // k 16..31
      const int scb = sub * 64;  // byte col of this subtile's V columns
      __builtin_amdgcn_s_setprio(1);
      {
        bf16x8 vf = *(const bf16x8*)swz(&vtbuf[cur][0][0], l31, scb + hi * 16);
        o0 = __builtin_amdgcn_mfma_f32_32x32x16_bf16(vf, f0.v, o0, 0, 0, 0);
        vf = *(const bf16x8*)swz(&vtbuf[cur][0][0], l31, scb + 32 + hi * 16);
        o0 = __builtin_amdgcn_mfma_f32_32x32x16_bf16(vf, f1.v, o0, 0, 0, 0);
        vf = *(const bf16x8*)swz(&vtbuf[cur][0][0], 32 + l31, scb + hi * 16);
        o1 = __builtin_amdgcn_mfma_f32_32x32x16_bf16(vf, f0.v, o1, 0, 0, 0);
        vf = *(const bf16x8*)swz(&vtbuf[cur][0][0], 32 + l31, scb + 32 + hi * 16);
        o1 = __builtin_amdgcn_mfma_f32_32x32x16_bf16(vf, f1.v, o1, 0, 0, 0);
      }
      __builtin_amdgcn_s_setprio(0);
    }

    if (have) {
      const int nxt = cur ^ 1;
      *(uint4*)swz(&kbuf[nxt][0][0], srow, sce * 2) = pka;
      *(uint4*)swz(&kbuf[nxt][0][0], srow, sce * 2 + 16) = pkc;
      *(uint4*)swz(&vtbuf[nxt][0][0], srow, sce * 2) = pva;
      *(uint4*)swz(&vtbuf[nxt][0][0], srow, sce * 2 + 16) = pvc;
      __syncthreads();
    }
    cur ^= 1;
  }

  // l-sum: lane and lane^32 hold complementary k-halves of the same q
  float la = la0 + la1 + la2 + la3;
  la += __shfl_xor(la, 32);
  const float scl = (SPLIT == 1) ? 1.f / la : 1.f;

  if constexpr (SPLIT > 1) {
    if (hi == 0)
      lbuf[(size_t)s * BH_ * N_ + (size_t)bh * N_ + qn + l31] = la;
  }

  __syncthreads();  // all PV reads done before reusing vtbuf for epilogue
  char* ep = (char*)&vtbuf[0][0][0] + wv * 4096;  // per-wave [32 q][64 d]
#pragma unroll
  for (int dt = 0; dt < 2; dt++) {
    const f32x16 o = dt ? o1 : o0;
#pragma unroll
    for (int g = 0; g < 4; g++) {
      bf16x4 o4;
#pragma unroll
      for (int j = 0; j < 4; j++) o4[j] = (__bf16)(o[4 * g + j] * scl);
      *(bf16x4*)swz(ep, l31, dt * 64 + 16 * g + 8 * hi) = o4;
    }
  }
  asm volatile("" ::: "memory");
  {
    __bf16* dst = pO + (size_t)s * PER_ + ((size_t)bh * N_ + qn) * D_;
#pragma unroll
    for (int i = 0; i < 4; i++) {
      const int row = i * 8 + (lane >> 3);
      uint4 v = *(const uint4*)swz(ep, row, (lane & 7) * 16);
      *(uint4*)((char*)dst + i * 1024 + lane * 16) = v;
    }
  }
}

// ---------------------------------------------------------------------------
// Combine: out = (O0 + O1) / (l0 + l1), elementwise over [BH][N][64].
// Written in place over p0 (each thread reads then writes its own elems).
// ---------------------------------------------------------------------------
__global__ __launch_bounds__(256) void combine_kernel(
    const __bf16* __restrict__ p0, const __bf16* __restrict__ p1,
    const float* __restrict__ l0, const float* __restrict__ l1,
    __bf16* __restrict__ outp) {
  const size_t idx8 = (size_t)blockIdx.x * 256 + threadIdx.x;  // 512K
  const size_t nidx = idx8 >> 3;
  bf16x8 a = *(const bf16x8*)&p0[idx8 * 8];
  bf16x8 b = *(const bf16x8*)&p1[idx8 * 8];
  const float inv = 1.f / (l0[nidx] + l1[nidx]);
  bf16x8 r;
#pragma unroll
  for (int e = 0; e < 8; e++) r[e] = (__bf16)(((float)a[e] + (float)b[e]) * inv);
  *(bf16x8*)&outp[idx8 * 8] = r;
}

extern "C" void kernel_launch(void* const* d_in, const int* in_sizes, int n_in,
                              void* d_out, int out_size, void* d_ws,
                              size_t ws_size, hipStream_t stream) {
  const float* query = (const float*)d_in[0];
  const float* key_ = (const float*)d_in[1];
  const float* value = (const float*)d_in[2];
  const float* wq = (const float*)d_in[3];
  const float* bq = (const float*)d_in[4];
  const float* wk = (const float*)d_in[5];
  const float* bk = (const float*)d_in[6];
  const float* wv = (const float*)d_in[7];
  const float* bv = (const float*)d_in[8];
  const float* wm = (const float*)d_in[9];
  const float* bm = (const float*)d_in[10];

  __bf16* qb = (__bf16*)d_ws;
  __bf16* kb = qb + PER_;
  __bf16* vtb = kb + PER_;
  __bf16* p0 = vtb + PER_;   // partial O split 0 / attout (combined in place)
  __bf16* p1 = p0 + PER_;    // partial O split 1
  float* lbuf = (float*)(p1 + PER_);        // [2][BH][N]
  __bf16* wfq = (__bf16*)(lbuf + 2 * BH_ * N_);
  __bf16* wfk = wfq + 65536;
  __bf16* wfv = wfk + 65536;
  __bf16* wfm = wfv + 65536;

  const size_t need_split = (size_t)((char*)(wfm + 65536) - (char*)d_ws);
  const bool use_split = ws_size >= need_split;

  dim3 blk(256);
  W4 wp{wq, wk, wv, wm, wfq, wfk, wfv, wfm};
  if (!use_split) {  // fallback layout: weights right after p0
    wfq = p1; wfk = wfq + 65536; wfv = wfk + 65536; wfm = wfv + 65536;
    wp = W4{wq, wk, wv, wm, wfq, wfk, wfv, wfm};
  }
  wcvt_kernel<<<dim3(32, 4), blk, 0, stream>>>(wp);

  qkv_fused_kernel<<<768, blk, 0, stream>>>(query, key_, value, wfq, wfk, wfv,
                                            bq, bk, bv, qb, kb, vtb);
  if (use_split) {
    attn_kernel<2><<<1024, blk, 0, stream>>>(qb, kb, vtb, p0, lbuf);
    combine_kernel<<<2048, blk, 0, stream>>>(p0, p1, lbuf, lbuf + BH_ * N_, p0);
  } else {
    attn_kernel<1><<<512, blk, 0, stream>>>(qb, kb, vtb, p0, nullptr);
  }
  final_proj_kernel<<<1024, blk, 0, stream>>>(p0, wfm, bm, (float*)d_out);
}

// Round 8
// 98.421 us; speedup vs baseline: 1.0919x; 1.0919x over previous
//
#include <hip/hip_runtime.h>
#include <hip/hip_bf16.h>

typedef float f32x4 __attribute__((ext_vector_type(4)));
typedef float f32x16 __attribute__((ext_vector_type(16)));
typedef __bf16 bf16x8 __attribute__((ext_vector_type(8)));
typedef __bf16 bf16x4 __attribute__((ext_vector_type(4)));
typedef unsigned int uint2v __attribute__((ext_vector_type(2)));
typedef unsigned int u32;

constexpr int B_ = 8, C_ = 256, N_ = 2048, H_ = 4, D_ = 64;
constexpr int BH_ = B_ * H_;  // 32
constexpr size_t PER_ = (size_t)BH_ * N_ * D_;  // 4M elems
constexpr float LOG2E = 1.44269504088896340736f;

static __device__ __forceinline__ float fast_exp2(float x) {
#if __has_builtin(__builtin_amdgcn_exp2f)
  return __builtin_amdgcn_exp2f(x);
#else
  return exp2f(x);
#endif
}

// XOR swizzle for [rows][128B] tiles: spread 16B slots across banks.
static __device__ __forceinline__ void* swz(void* base, int row, int cb) {
  return (char*)base + row * 128 + (cb ^ ((row & 7) << 4));
}
static __device__ __forceinline__ const void* swz(const void* base, int row, int cb) {
  return (const char*)base + row * 128 + (cb ^ ((row & 7) << 4));
}

// async global->LDS, 16B per lane. LDS dst: wave-uniform base + lane*16.
static __device__ __forceinline__ void gload16(void* lds, const void* g) {
  __builtin_amdgcn_global_load_lds(
      (const __attribute__((address_space(1))) u32*)g,
      (__attribute__((address_space(3))) u32*)lds, 16, 0, 0);
}

// ---------------------------------------------------------------------------
// W pre-convert -> bf16 A-fragment order (16x16 frags for the GEMM kernels).
// ---------------------------------------------------------------------------
struct W4 {
  const float* s0; const float* s1; const float* s2; const float* s3;
  __bf16* d0; __bf16* d1; __bf16* d2; __bf16* d3;
};

__global__ __launch_bounds__(256) void wcvt_kernel(W4 p) {
  const int m = blockIdx.y;
  const float* src = m == 0 ? p.s0 : m == 1 ? p.s1 : m == 2 ? p.s2 : p.s3;
  __bf16* dst = m == 0 ? p.d0 : m == 1 ? p.d1 : m == 2 ? p.d2 : p.d3;
  const int f = blockIdx.x * 256 + threadIdx.x;  // 0..8191 fragment ids
  const int o_blk = f >> 9;
  const int ks = (f >> 6) & 7;
  const int lane = f & 63;
  const int row = o_blk * 16 + (lane & 15);
  const int kbase = ks * 32 + (lane >> 4) * 8;
  bf16x8 v;
  if (m == 3) {
    for (int e = 0; e < 8; e++) {
      const int k = kbase + e;
      const int c = ((k & 63) << 2) | (k >> 6);
      v[e] = (__bf16)src[row * 256 + c];
    }
  } else {
    const int srow = ((row & 63) << 2) | (row >> 6);  // orig channel d*4+h
    const float* s = src + srow * 256 + kbase;
    float4 a = *(const float4*)s;
    float4 b = *(const float4*)(s + 4);
    v[0] = (__bf16)a.x; v[1] = (__bf16)a.y; v[2] = (__bf16)a.z; v[3] = (__bf16)a.w;
    v[4] = (__bf16)b.x; v[5] = (__bf16)b.y; v[6] = (__bf16)b.z; v[7] = (__bf16)b.w;
  }
  *(bf16x8*)&dst[(size_t)f * 8] = v;
}

// ---------------------------------------------------------------------------
// Fused QKV projection. Q -> row-major [bh][n][64] bf16 (scaled, exp2 dom).
// K,V^T -> PRE-SWIZZLED 8KB tiles: per (bh, kvtile of 64): K byte
// (n&63)*128 + (2d ^ ((n&7)<<4)); V^T byte d*128 + (2(n&63) ^ ((d&7)<<4)).
// These match attn's swizzled LDS reads so staging is a linear async copy.
// ---------------------------------------------------------------------------
__global__ __launch_bounds__(256) void qkv_fused_kernel(
    const float* __restrict__ xq, const float* __restrict__ xk,
    const float* __restrict__ xv, const __bf16* __restrict__ wfq,
    const __bf16* __restrict__ wfk, const __bf16* __restrict__ wfv,
    const float* __restrict__ bq, const float* __restrict__ bk,
    const float* __restrict__ bv, __bf16* __restrict__ oq,
    char* __restrict__ oksw, char* __restrict__ ovsw) {
  __shared__ __bf16 xlds[64][264];

  const int m = blockIdx.x >> 8;
  int inner = blockIdx.x & 255;
  inner = (inner & 7) * 32 + (inner >> 3);  // bijective XCD swizzle (256=8*32)
  const int b = inner >> 5, nb = inner & 31;
  const int n0 = nb * 64;

  const float* xf = m == 0 ? xq : m == 1 ? xk : xv;
  const __bf16* wf = m == 0 ? wfq : m == 1 ? wfk : wfv;
  const float* bias = m == 0 ? bq : m == 1 ? bk : bv;
  const float scale = m == 0 ? 0.125f * LOG2E : 1.0f;

  const int t = threadIdx.x;
  {
    const int kl = t >> 4;         // 0..15
    const int nl = (t & 15) * 4;   // 0,4,..,60
    const float* src = xf + (size_t)b * C_ * N_ + n0 + nl;
    for (int it = 0; it < 16; it++) {
      const int k = it * 16 + kl;
      float4 f = *(const float4*)(src + (size_t)k * N_);
      xlds[nl + 0][k] = (__bf16)f.x;
      xlds[nl + 1][k] = (__bf16)f.y;
      xlds[nl + 2][k] = (__bf16)f.z;
      xlds[nl + 3][k] = (__bf16)f.w;
    }
  }
  __syncthreads();

  const int lane = t & 63, wvv = t >> 6;
  const int wm = wvv >> 1, wn = wvv & 1;   // wave: 128 o x 32 n
  const int l15 = lane & 15, lg = lane >> 4;

  f32x4 acc[8][2] = {};

  for (int ks = 0; ks < 8; ks++) {
    bf16x8 bfr[2];
    for (int ni = 0; ni < 2; ni++)
      bfr[ni] = *(const bf16x8*)&xlds[wn * 32 + ni * 16 + l15][ks * 32 + lg * 8];
    for (int mi = 0; mi < 8; mi++) {
      bf16x8 af = *(const bf16x8*)&wf[(((size_t)(wm * 8 + mi) * 8 + ks) * 64 + lane) * 8];
      acc[mi][0] = __builtin_amdgcn_mfma_f32_16x16x32_bf16(af, bfr[0], acc[mi][0], 0, 0, 0);
      acc[mi][1] = __builtin_amdgcn_mfma_f32_16x16x32_bf16(af, bfr[1], acc[mi][1], 0, 0, 0);
    }
  }

  for (int mi = 0; mi < 8; mi++) {
    const int h = wm * 2 + (mi >> 2);
    const int d0 = (mi & 3) * 16 + 4 * lg;
    for (int ni = 0; ni < 2; ni++) {
      const int n = n0 + wn * 32 + ni * 16 + l15;
      const size_t tbase = ((size_t)(b * H_ + h) * (N_ / 64) + (n >> 6)) * 8192;
      if (m == 0) {
        bf16x4 o4;
        for (int r = 0; r < 4; r++)
          o4[r] = (__bf16)((acc[mi][ni][r] + bias[((d0 + r) << 2) | h]) * scale);
        *(bf16x4*)&oq[((size_t)(b * H_ + h) * N_ + n) * D_ + d0] = o4;
      } else if (m == 1) {
        bf16x4 o4;
        for (int r = 0; r < 4; r++)
          o4[r] = (__bf16)(acc[mi][ni][r] + bias[((d0 + r) << 2) | h]);
        *(bf16x4*)swz(oksw + tbase, n & 63, 2 * d0) = o4;
      } else {
        for (int r = 0; r < 4; r++)
          *(__bf16*)swz(ovsw + tbase, d0 + r, 2 * (n & 63)) =
              (__bf16)(acc[mi][ni][r] + bias[((d0 + r) << 2) | h]);
      }
    }
  }
}

// ---------------------------------------------------------------------------
// Final projection: y[o,n] = sum_k w'[o,k]*attout[.] + bm[o], f32 out.
// attout layout: [b*H+h][n][64] with k = h*64+d.
// ---------------------------------------------------------------------------
__global__ __launch_bounds__(256) void final_proj_kernel(
    const __bf16* __restrict__ xb, const __bf16* __restrict__ wf,
    const float* __restrict__ bias, float* __restrict__ out) {
  const int bid = blockIdx.x;
  const int wid = (bid & 7) * 128 + (bid >> 3);
  const int o_t = wid & 3;
  const int nb = (wid >> 2) & 31;
  const int b = wid >> 7;
  const int o0 = o_t * 64, n0 = nb * 64;
  const int t = threadIdx.x, lane = t & 63;
  const int wvv = t >> 6, wm = wvv >> 1, wn = wvv & 1;
  const int l15 = lane & 15, lg = lane >> 4;
  const int nbase = n0 + wn * 32 + l15;

  f32x4 acc[2][2] = {};

  for (int ks = 0; ks < 8; ks++) {
    bf16x8 af[2];
    for (int mi = 0; mi < 2; mi++)
      af[mi] = *(const bf16x8*)&wf[(((size_t)(o_t * 4 + wm * 2 + mi) * 8 + ks) * 64 + lane) * 8];
    bf16x8 bfr[2];
    const size_t bh = (size_t)(b * H_ + (ks >> 1));
    const int d0 = (ks & 1) * 32 + lg * 8;
    for (int ni = 0; ni < 2; ni++)
      bfr[ni] = *(const bf16x8*)&xb[(bh * N_ + nbase + ni * 16) * D_ + d0];
    for (int mi = 0; mi < 2; mi++)
      for (int ni = 0; ni < 2; ni++)
        acc[mi][ni] = __builtin_amdgcn_mfma_f32_16x16x32_bf16(
            af[mi], bfr[ni], acc[mi][ni], 0, 0, 0);
  }

  for (int mi = 0; mi < 2; mi++) {
    for (int r = 0; r < 4; r++) {
      const int och = o0 + wm * 32 + mi * 16 + 4 * lg + r;
      const float bv_ = bias[och];
      for (int ni = 0; ni < 2; ni++) {
        const int n = n0 + wn * 32 + ni * 16 + l15;
        out[((size_t)b * C_ + och) * N_ + n] = acc[mi][ni][r] + bv_;
      }
    }
  }
}

// ---------------------------------------------------------------------------
// Flash attention: 8 waves x 32 q = 256 q/block; K/V staged via async
// global_load_lds from pre-swizzled tiles (no ds_writes, no staging regs).
// 32x32 MFMA, in-register P (permlane32_swap), maxless softmax (exp2 dom).
// SPLIT-way KV split writes unnormalized partial O + l; combine normalizes.
// ---------------------------------------------------------------------------
template <int SPLIT>
__global__ __launch_bounds__(512) void attn_kernel(
    const __bf16* __restrict__ qb, const char* __restrict__ kbsw,
    const char* __restrict__ vtsw, __bf16* __restrict__ pO,
    float* __restrict__ lbuf) {
  __shared__ char smem[32768];  // [0]:K dbuf 2x8KB  [16384]:V dbuf 2x8KB

  const int t = threadIdx.x, lane = t & 63, wv = t >> 6;  // wv 0..7
  const int l31 = lane & 31, hi = lane >> 5;

  const int bid = blockIdx.x;  // 256*SPLIT blocks
  const int per_xcd = (256 * SPLIT) / 8;
  const int wid = (bid & 7) * per_xcd + (bid >> 3);  // 4 bh per XCD
  const int bh = wid / (8 * SPLIT);
  const int rem = wid % (8 * SPLIT);
  const int qt = rem & 7;
  const int s = rem >> 3;
  const int qn = qt * 256 + wv * 32;  // wave's 32 q rows
  constexpr int NT = N_ / SPLIT / 64; // tiles per block
  const int jt0 = s * NT;

  const char* ktiles = kbsw + (size_t)bh * (N_ / 64) * 8192;
  const char* vtiles = vtsw + (size_t)bh * (N_ / 64) * 8192;

  // Q B-frags: qf[i] = Q[q=qn+l31][d = i*16 + hi*8 .. +7]
  const __bf16* qrow = qb + ((size_t)bh * N_ + qn + l31) * D_;
  bf16x8 qf[4];
#pragma unroll
  for (int i = 0; i < 4; i++) qf[i] = *(const bf16x8*)(qrow + i * 16 + hi * 8);

  // stage tile jt_g into buffer bb (2 async 16B loads/thread)
  auto stage = [&](int jt_g, int bb) {
    gload16(smem + bb * 8192 + t * 16, ktiles + (size_t)jt_g * 8192 + t * 16);
    gload16(smem + 16384 + bb * 8192 + t * 16,
            vtiles + (size_t)jt_g * 8192 + t * 16);
  };

  stage(jt0, 0);
  __syncthreads();  // drains vmcnt -> tile 0 resident

  f32x16 o0 = {}, o1 = {};
  float la0 = 0.f, la1 = 0.f, la2 = 0.f, la3 = 0.f;
  int cur = 0;

  for (int jt = 0; jt < NT; jt++) {
    if (jt + 1 < NT) stage(jt0 + jt + 1, cur ^ 1);
    const char* kc = smem + cur * 8192;
    const char* vc = smem + 16384 + cur * 8192;

    // QK: two 32x32 S-subtiles
    f32x16 s0 = {}, s1 = {};
    __builtin_amdgcn_s_setprio(1);
#pragma unroll
    for (int i = 0; i < 4; i++) {
      bf16x8 kf = *(const bf16x8*)swz(kc, l31, i * 32 + hi * 16);
      s0 = __builtin_amdgcn_mfma_f32_32x32x16_bf16(kf, qf[i], s0, 0, 0, 0);
    }
#pragma unroll
    for (int i = 0; i < 4; i++) {
      bf16x8 kf = *(const bf16x8*)swz(kc, 32 + l31, i * 32 + hi * 16);
      s1 = __builtin_amdgcn_mfma_f32_32x32x16_bf16(kf, qf[i], s1, 0, 0, 0);
    }
    __builtin_amdgcn_s_setprio(0);

    // per-subtile: exp2 -> pack bf16 pairs -> permlane32_swap -> PV
#pragma unroll
    for (int sub = 0; sub < 2; sub++) {
      const f32x16 sv = sub ? s1 : s0;
      float pr[16];
#pragma unroll
      for (int r = 0; r < 16; r++) pr[r] = fast_exp2(sv[r]);
      la0 += pr[0] + pr[4] + pr[8] + pr[12];
      la1 += pr[1] + pr[5] + pr[9] + pr[13];
      la2 += pr[2] + pr[6] + pr[10] + pr[14];
      la3 += pr[3] + pr[7] + pr[11] + pr[15];
      unsigned w[8];
#pragma unroll
      for (int g = 0; g < 8; g++) {
        union { __bf16 h[2]; unsigned u; } cv;
        cv.h[0] = (__bf16)pr[2 * g];
        cv.h[1] = (__bf16)pr[2 * g + 1];
        w[g] = cv.u;
      }
      uint2v r0 = __builtin_amdgcn_permlane32_swap(w[0], w[2], false, false);
      uint2v r1 = __builtin_amdgcn_permlane32_swap(w[1], w[3], false, false);
      uint2v r2 = __builtin_amdgcn_permlane32_swap(w[4], w[6], false, false);
      uint2v r3 = __builtin_amdgcn_permlane32_swap(w[5], w[7], false, false);
      union { unsigned u[4]; bf16x8 v; } f0 = {{r0.x, r1.x, r0.y, r1.y}};  // k 0..15
      union { unsigned u[4]; bf16x8 v; } f1 = {{r2.x, r3.x, r2.y, r3.y}};  // k 16..31
      const int scb = sub * 64;
      __builtin_amdgcn_s_setprio(1);
      {
        bf16x8 vf = *(const bf16x8*)swz(vc, l31, scb + hi * 16);
        o0 = __builtin_amdgcn_mfma_f32_32x32x16_bf16(vf, f0.v, o0, 0, 0, 0);
        vf = *(const bf16x8*)swz(vc, l31, scb + 32 + hi * 16);
        o0 = __builtin_amdgcn_mfma_f32_32x32x16_bf16(vf, f1.v, o0, 0, 0, 0);
        vf = *(const bf16x8*)swz(vc, 32 + l31, scb + hi * 16);
        o1 = __builtin_amdgcn_mfma_f32_32x32x16_bf16(vf, f0.v, o1, 0, 0, 0);
        vf = *(const bf16x8*)swz(vc, 32 + l31, scb + 32 + hi * 16);
        o1 = __builtin_amdgcn_mfma_f32_32x32x16_bf16(vf, f1.v, o1, 0, 0, 0);
      }
      __builtin_amdgcn_s_setprio(0);
    }

    __syncthreads();  // drains vmcnt (next tile landed) + gates buf reuse
    cur ^= 1;
  }

  // l-sum: lane and lane^32 hold complementary k-halves of the same q
  float la = la0 + la1 + la2 + la3;
  la += __shfl_xor(la, 32);
  const float scl = (SPLIT == 1) ? 1.f / la : 1.f;

  if constexpr (SPLIT > 1) {
    if (hi == 0)
      lbuf[(size_t)s * BH_ * N_ + (size_t)bh * N_ + qn + l31] = la;
  }

  // epilogue: per-wave transpose in (now free) smem, coalesced store
  char* ep = smem + wv * 4096;  // per-wave [32 q][64 d]
#pragma unroll
  for (int dt = 0; dt < 2; dt++) {
    const f32x16 o = dt ? o1 : o0;
#pragma unroll
    for (int g = 0; g < 4; g++) {
      bf16x4 o4;
#pragma unroll
      for (int j = 0; j < 4; j++) o4[j] = (__bf16)(o[4 * g + j] * scl);
      *(bf16x4*)swz(ep, l31, dt * 64 + 16 * g + 8 * hi) = o4;
    }
  }
  asm volatile("" ::: "memory");
  {
    __bf16* dst = pO + (size_t)s * PER_ + ((size_t)bh * N_ + qn) * D_;
#pragma unroll
    for (int i = 0; i < 4; i++) {
      const int row = i * 8 + (lane >> 3);
      uint4 v = *(const uint4*)swz(ep, row, (lane & 7) * 16);
      *(uint4*)((char*)dst + i * 1024 + lane * 16) = v;
    }
  }
}

// ---------------------------------------------------------------------------
// Combine: out = (O0 + O1) / (l0 + l1), elementwise over [BH][N][64].
// ---------------------------------------------------------------------------
__global__ __launch_bounds__(256) void combine_kernel(
    const __bf16* __restrict__ p0, const __bf16* __restrict__ p1,
    const float* __restrict__ l0, const float* __restrict__ l1,
    __bf16* __restrict__ outp) {
  const size_t idx8 = (size_t)blockIdx.x * 256 + threadIdx.x;  // 512K
  const size_t nidx = idx8 >> 3;
  bf16x8 a = *(const bf16x8*)&p0[idx8 * 8];
  bf16x8 b = *(const bf16x8*)&p1[idx8 * 8];
  const float inv = 1.f / (l0[nidx] + l1[nidx]);
  bf16x8 r;
#pragma unroll
  for (int e = 0; e < 8; e++) r[e] = (__bf16)(((float)a[e] + (float)b[e]) * inv);
  *(bf16x8*)&outp[idx8 * 8] = r;
}

extern "C" void kernel_launch(void* const* d_in, const int* in_sizes, int n_in,
                              void* d_out, int out_size, void* d_ws,
                              size_t ws_size, hipStream_t stream) {
  const float* query = (const float*)d_in[0];
  const float* key_ = (const float*)d_in[1];
  const float* value = (const float*)d_in[2];
  const float* wq = (const float*)d_in[3];
  const float* bq = (const float*)d_in[4];
  const float* wk = (const float*)d_in[5];
  const float* bk = (const float*)d_in[6];
  const float* wv = (const float*)d_in[7];
  const float* bv = (const float*)d_in[8];
  const float* wm = (const float*)d_in[9];
  const float* bm = (const float*)d_in[10];

  __bf16* qb = (__bf16*)d_ws;                 // 8 MB, [bh][n][64]
  char* kbsw = (char*)(qb + PER_);            // 8 MB, swizzled tiles
  char* vtsw = kbsw + PER_ * 2;               // 8 MB, swizzled tiles
  __bf16* p0 = (__bf16*)(vtsw + PER_ * 2);    // 8 MB partial O s=0 / combined
  __bf16* p1 = p0 + PER_;                     // 8 MB partial O s=1
  float* lbuf = (float*)(p1 + PER_);          // [2][BH][N]
  __bf16* wfq = (__bf16*)(lbuf + 2 * BH_ * N_);
  __bf16* wfk = wfq + 65536;
  __bf16* wfv = wfk + 65536;
  __bf16* wfm = wfv + 65536;

  const size_t need_split = (size_t)((char*)(wfm + 65536) - (char*)d_ws);
  const bool use_split = ws_size >= need_split;

  dim3 blk(256);
  W4 wp{wq, wk, wv, wm, wfq, wfk, wfv, wfm};
  if (!use_split) {  // fallback layout: weights right after p0
    wfq = p1; wfk = wfq + 65536; wfv = wfk + 65536; wfm = wfv + 65536;
    wp = W4{wq, wk, wv, wm, wfq, wfk, wfv, wfm};
  }
  wcvt_kernel<<<dim3(32, 4), blk, 0, stream>>>(wp);

  qkv_fused_kernel<<<768, blk, 0, stream>>>(query, key_, value, wfq, wfk, wfv,
                                            bq, bk, bv, qb, kbsw, vtsw);
  if (use_split) {
    attn_kernel<2><<<512, dim3(512), 0, stream>>>(qb, kbsw, vtsw, p0, lbuf);
    combine_kernel<<<2048, blk, 0, stream>>>(p0, p1, lbuf, lbuf + BH_ * N_, p0);
  } else {
    attn_kernel<1><<<256, dim3(512), 0, stream>>>(qb, kbsw, vtsw, p0, nullptr);
  }
  final_proj_kernel<<<1024, blk, 0, stream>>>(p0, wfm, bm, (float*)d_out);
}